// Round 9
// baseline (754.078 us; speedup 1.0000x reference)
//
#include <hip/hip_runtime.h>
#include <hip/hip_fp16.h>

#define N_NODES 100000
#define E_EDGES 1600000
#define E4 (E_EDGES / 4)                       // 400000
#define NBUCKETS ((N_NODES + 127) / 128)       // 782
#define CHUNK 8192
#define NCHUNK ((E_EDGES + CHUNK - 1) / CHUNK) // 196
#define HM (NBUCKETS * NCHUNK)                 // 153272
#define NSB ((HM + 1023) / 1024)               // 150

// ---------------------------------------------------------------------------
// GEMM (round-5 proven): H[N,DOUT] = act(X)[N,64] @ W[64,DOUT], fp16 output.
// SLICED=true stores channel-sliced: Hs[slice=c>>3][node][c&7]  (16B rows).
// ---------------------------------------------------------------------------
template<int DOUT, bool RELU_IN, bool SLICED>
__global__ __launch_bounds__(256) void gemm_tile(const float* __restrict__ X,
                                                 const float* __restrict__ W,
                                                 __half* __restrict__ H) {
    __shared__ float Xs[64][68];
    __shared__ float Ws[64 * DOUT];
    const int tid = threadIdx.x;

    for (int i = tid; i < 64 * DOUT / 4; i += 256) {
        reinterpret_cast<float4*>(Ws)[i] = reinterpret_cast<const float4*>(W)[i];
    }

    const int row0 = blockIdx.x * 64;
#pragma unroll
    for (int p = 0; p < 4; ++p) {
        int idx = p * 256 + tid;
        int r = idx >> 4;
        int c = (idx & 15) << 2;
        float4 v = make_float4(0.f, 0.f, 0.f, 0.f);
        if (row0 + r < N_NODES) {
            v = *reinterpret_cast<const float4*>(X + (size_t)(row0 + r) * 64 + c);
        }
        if (RELU_IN) {
            v.x = fmaxf(v.x, 0.f); v.y = fmaxf(v.y, 0.f);
            v.z = fmaxf(v.z, 0.f); v.w = fmaxf(v.w, 0.f);
        }
        *reinterpret_cast<float4*>(&Xs[r][c]) = v;
    }
    __syncthreads();

    const int tr = (tid >> 4) << 2;
    const int tc = (tid & 15) << 2;
    if (tc < DOUT) {
        float acc[4][4];
#pragma unroll
        for (int i = 0; i < 4; ++i)
#pragma unroll
            for (int j = 0; j < 4; ++j) acc[i][j] = 0.f;

#pragma unroll 8
        for (int k = 0; k < 64; ++k) {
            float4 wv = *reinterpret_cast<const float4*>(&Ws[k * DOUT + tc]);
            float xv[4];
#pragma unroll
            for (int i = 0; i < 4; ++i) xv[i] = Xs[tr + i][k];
#pragma unroll
            for (int i = 0; i < 4; ++i) {
                acc[i][0] += xv[i] * wv.x;
                acc[i][1] += xv[i] * wv.y;
                acc[i][2] += xv[i] * wv.z;
                acc[i][3] += xv[i] * wv.w;
            }
        }
#pragma unroll
        for (int i = 0; i < 4; ++i) {
            int r = row0 + tr + i;
            if (r < N_NODES) {
                union { __half2 h2[2]; uint2 u; } pk;
                pk.h2[0] = __halves2half2(__float2half(acc[i][0]), __float2half(acc[i][1]));
                pk.h2[1] = __halves2half2(__float2half(acc[i][2]), __float2half(acc[i][3]));
                if (SLICED) {
                    // channels tc..tc+3 all lie in slice tc>>3 (tc % 4 == 0)
                    __half* p = H + ((size_t)(tc >> 3) * N_NODES + (size_t)r) * 8 + (tc & 7);
                    *reinterpret_cast<uint2*>(p) = pk.u;
                } else {
                    *reinterpret_cast<uint2*>(H + (size_t)r * DOUT + tc) = pk.u;
                }
            }
        }
    }
}

// ---------------------------------------------------------------------------
// CSR build v3: chunked counting sort, NO global atomics. (round-5 proven)
// ---------------------------------------------------------------------------
__global__ __launch_bounds__(256) void chunk_hist(const int4* __restrict__ dst4,
                                                  int* __restrict__ histM) {
    __shared__ int lh[NBUCKETS];
    const int tid = threadIdx.x, c = blockIdx.x;
    for (int i = tid; i < NBUCKETS; i += 256) lh[i] = 0;
    __syncthreads();
    const int q0 = c * (CHUNK / 4);
    for (int q = tid; q < CHUNK / 4; q += 256) {
        if (q0 + q < E4) {
            int4 d = dst4[q0 + q];
            atomicAdd(&lh[d.x >> 7], 1);
            atomicAdd(&lh[d.y >> 7], 1);
            atomicAdd(&lh[d.z >> 7], 1);
            atomicAdd(&lh[d.w >> 7], 1);
        }
    }
    __syncthreads();
    for (int i = tid; i < NBUCKETS; i += 256) histM[i * NCHUNK + c] = lh[i];
}

__global__ __launch_bounds__(256) void scan_blocks(const int* __restrict__ in,
                                                   int* __restrict__ out,
                                                   int* __restrict__ bsums) {
    __shared__ int wsum[4];
    const int tid = threadIdx.x, lane = tid & 63, wv = tid >> 6;
    const int base = blockIdx.x * 1024 + tid * 4;
    int v[4];
    int s = 0;
#pragma unroll
    for (int j = 0; j < 4; ++j) {
        v[j] = (base + j < HM) ? in[base + j] : 0;
        s += v[j];
    }
    int inc = s;
#pragma unroll
    for (int o = 1; o < 64; o <<= 1) {
        int t = __shfl_up(inc, o, 64);
        if (lane >= o) inc += t;
    }
    if (lane == 63) wsum[wv] = inc;
    __syncthreads();
    int woff = 0;
    for (int w2 = 0; w2 < wv; ++w2) woff += wsum[w2];
    int run = woff + inc - s;
#pragma unroll
    for (int j = 0; j < 4; ++j) {
        if (base + j < HM) out[base + j] = run;
        run += v[j];
    }
    if (tid == 255) bsums[blockIdx.x] = woff + inc;
}

__global__ __launch_bounds__(256) void scan_mid256(const int* __restrict__ bs,
                                                   int* __restrict__ boff) {
    __shared__ int wsum[4];
    const int tid = threadIdx.x, lane = tid & 63, wv = tid >> 6;
    int v = (tid < NSB) ? bs[tid] : 0;
    int inc = v;
#pragma unroll
    for (int o = 1; o < 64; o <<= 1) {
        int t = __shfl_up(inc, o, 64);
        if (lane >= o) inc += t;
    }
    if (lane == 63) wsum[wv] = inc;
    __syncthreads();
    int woff = 0;
    for (int w2 = 0; w2 < wv; ++w2) woff += wsum[w2];
    if (tid < NSB) boff[tid] = woff + inc - v;
}

__global__ __launch_bounds__(256) void scan_add(int* __restrict__ out,
                                                const int* __restrict__ boff) {
    const int base = blockIdx.x * 1024 + threadIdx.x * 4;
    const int a = boff[blockIdx.x];
#pragma unroll
    for (int j = 0; j < 4; ++j) {
        if (base + j < HM) out[base + j] += a;
    }
}

__global__ __launch_bounds__(256) void chunk_scatter(const int4* __restrict__ src4,
                                                     const int4* __restrict__ dst4,
                                                     const float4* __restrict__ ew4,
                                                     const int* __restrict__ hs,
                                                     int2* __restrict__ tmp) {
    __shared__ int lcur[NBUCKETS];
    const int tid = threadIdx.x, c = blockIdx.x;
    for (int i = tid; i < NBUCKETS; i += 256) lcur[i] = hs[i * NCHUNK + c];
    __syncthreads();
    const int q0 = c * (CHUNK / 4);
    for (int q = tid; q < CHUNK / 4; q += 256) {
        if (q0 + q < E4) {
            int4 s = src4[q0 + q];
            int4 d = dst4[q0 + q];
            float4 w = ew4[q0 + q];
            int p0 = atomicAdd(&lcur[d.x >> 7], 1);
            tmp[p0] = make_int2(s.x | ((d.x & 127) << 17), __float_as_int(w.x));
            int p1 = atomicAdd(&lcur[d.y >> 7], 1);
            tmp[p1] = make_int2(s.y | ((d.y & 127) << 17), __float_as_int(w.y));
            int p2 = atomicAdd(&lcur[d.z >> 7], 1);
            tmp[p2] = make_int2(s.z | ((d.z & 127) << 17), __float_as_int(w.z));
            int p3 = atomicAdd(&lcur[d.w >> 7], 1);
            tmp[p3] = make_int2(s.w | ((d.w & 127) << 17), __float_as_int(w.w));
        }
    }
}

__global__ __launch_bounds__(256) void build_csr(const int2* __restrict__ tmp,
                                                 const int* __restrict__ hs,
                                                 int* __restrict__ off,
                                                 int2* __restrict__ csr) {
    __shared__ int lhist[128];
    __shared__ int lcur[128];
    __shared__ int wtot[4];
    const int b = blockIdx.x;
    const int tid = threadIdx.x, lane = tid & 63, wv = tid >> 6;
    const int base = hs[b * NCHUNK];
    const int end  = (b + 1 < NBUCKETS) ? hs[(b + 1) * NCHUNK] : E_EDGES;

    if (tid < 128) lhist[tid] = 0;
    __syncthreads();

    for (int e = base + tid; e < end; e += 256) {
        int dl = (tmp[e].x >> 17) & 127;
        atomicAdd(&lhist[dl], 1);
    }
    __syncthreads();

    int v = (tid < 128) ? lhist[tid] : 0;
    int inc = v;
#pragma unroll
    for (int o = 1; o < 64; o <<= 1) {
        int t = __shfl_up(inc, o, 64);
        if (lane >= o) inc += t;
    }
    if (lane == 63) wtot[wv] = inc;
    __syncthreads();
    if (tid < 128) {
        int excl = inc - v + ((wv == 1) ? wtot[0] : 0);
        lcur[tid] = base + excl;
        int node = b * 128 + tid;
        if (node < N_NODES) off[node] = base + excl;
    }
    if (b == NBUCKETS - 1 && tid == 0) off[N_NODES] = E_EDGES;
    __syncthreads();

    for (int e = base + tid; e < end; e += 256) {
        int2 t2 = tmp[e];
        int dl = (t2.x >> 17) & 127;
        int p = atomicAdd(&lcur[dl], 1);
        csr[p] = make_int2(t2.x & 0x1FFFF, t2.y);
    }
}

// ---------------------------------------------------------------------------
// Aggregate SLICED: slice = blockIdx & 7 (XCD round-robin -> per-XCD slice
// working set 1.6 MB, L2-resident). Lane = (edge e = lane>>2, chan-pair cp =
// lane&3). 16 edges in flight per instruction; per-lane weights (no readlane).
// shfl_xor tree folds edges. AGG[node][slice*8 + 2cp..] = sum + bias.
// ---------------------------------------------------------------------------
__global__ __launch_bounds__(256) void aggregate_sliced(const __half* __restrict__ Hs,
                                                        const int* __restrict__ off,
                                                        const int2* __restrict__ csr,
                                                        const float* __restrict__ bvec,
                                                        float* __restrict__ AGG) {
    const int bid = blockIdx.x;
    const int slice = bid & 7;
    const int chunk = bid >> 3;
    const int tid = threadIdx.x, lane = tid & 63, wv = tid >> 6;
    const int e  = lane >> 2;               // 0..15
    const int cp = lane & 3;                // channel pair within slice
    const float b0 = bvec[slice * 8 + cp * 2];
    const float b1 = bvec[slice * 8 + cp * 2 + 1];
    const __half* Hbase = Hs + (size_t)slice * N_NODES * 8 + cp * 2;

#pragma unroll 1
    for (int i = 0; i < 4; ++i) {
        const int node = chunk * 16 + wv * 4 + i;
        if (node >= N_NODES) return;
        const int k0 = __builtin_amdgcn_readfirstlane(off[node]);
        const int k1 = __builtin_amdgcn_readfirstlane(off[node + 1]);
        float ax = 0.f, ay = 0.f;
        for (int t = k0; t < k1; t += 16) {
            const int idx = t + e;
            const bool vld = idx < k1;
            int2 ec = csr[vld ? idx : k0];
            const float w = vld ? __int_as_float(ec.y) : 0.f;
            float2 hf = __half22float2(
                *reinterpret_cast<const __half2*>(Hbase + (size_t)ec.x * 8));
            ax += hf.x * w;
            ay += hf.y * w;
        }
#pragma unroll
        for (int o2 = 4; o2 < 64; o2 <<= 1) {
            ax += __shfl_xor(ax, o2);
            ay += __shfl_xor(ay, o2);
        }
        if (lane < 4) {   // lane == cp, e == 0
            *reinterpret_cast<float2*>(AGG + (size_t)node * 64 + slice * 8 + cp * 2) =
                make_float2(ax + b0, ay + b1);
        }
    }
}

// ---------------------------------------------------------------------------
// Aggregate (round-5 proven, node-major): used for the final 40-ch layer.
// ---------------------------------------------------------------------------
template<int DOUT>
__global__ __launch_bounds__(256) void aggregate(const __half* __restrict__ H,
                                                 const int* __restrict__ off,
                                                 const int2* __restrict__ csr,
                                                 const float* __restrict__ bvec,
                                                 float* __restrict__ AGG) {
    const int node = (int)((blockIdx.x * 256 + threadIdx.x) >> 6);
    const int lane = threadIdx.x & 63;
    if (node >= N_NODES) return;
    const int k0 = __builtin_amdgcn_readfirstlane(off[node]);
    const int k1 = __builtin_amdgcn_readfirstlane(off[node + 1]);
    const bool active = (DOUT == 64) || (lane < DOUT);
    float acc = active ? bvec[lane] : 0.f;
    int k = k0;
    for (; k + 3 < k1; k += 4) {
        int2 e0 = csr[k], e1 = csr[k + 1], e2 = csr[k + 2], e3 = csr[k + 3];
        int s0 = __builtin_amdgcn_readfirstlane(e0.x);
        int s1 = __builtin_amdgcn_readfirstlane(e1.x);
        int s2 = __builtin_amdgcn_readfirstlane(e2.x);
        int s3 = __builtin_amdgcn_readfirstlane(e3.x);
        float h0 = 0.f, h1 = 0.f, h2 = 0.f, h3 = 0.f;
        if (active) {
            h0 = __half2float(H[(size_t)s0 * DOUT + lane]);
            h1 = __half2float(H[(size_t)s1 * DOUT + lane]);
            h2 = __half2float(H[(size_t)s2 * DOUT + lane]);
            h3 = __half2float(H[(size_t)s3 * DOUT + lane]);
        }
        acc += h0 * __int_as_float(e0.y) + h1 * __int_as_float(e1.y)
             + h2 * __int_as_float(e2.y) + h3 * __int_as_float(e3.y);
    }
    for (; k < k1; ++k) {
        int2 e0 = csr[k];
        int s0 = __builtin_amdgcn_readfirstlane(e0.x);
        if (active) acc += __half2float(H[(size_t)s0 * DOUT + lane]) * __int_as_float(e0.y);
    }
    if (active) AGG[(size_t)node * DOUT + lane] = acc;
}

// ---------------------------------------------------------------------------
extern "C" void kernel_launch(void* const* d_in, const int* in_sizes, int n_in,
                              void* d_out, int out_size, void* d_ws, size_t ws_size,
                              hipStream_t stream) {
    const float* x    = (const float*)d_in[0];
    const float* ew   = (const float*)d_in[1];
    const float* W    = (const float*)d_in[2];   // [4,64,64]
    const float* b    = (const float*)d_in[3];   // [4,64]
    const float* Wout = (const float*)d_in[4];   // [64,40]
    const float* bout = (const float*)d_in[5];   // [40]
    const int*   src  = (const int*)d_in[6];
    const int*   dst  = (const int*)d_in[7];
    float* out = (float*)d_out;

    // workspace layout (tmp aliases H2: tmp fully consumed by build_csr
    // before the first gemm writes H2; stream order guarantees this)
    char* wsp = (char*)d_ws;
    __half* H2  = (__half*)wsp;                                   // N*64 half (12.8 MB)
    int2*   tmp = (int2*)wsp;                                     // E int2    (12.8 MB) alias
    size_t  o   = (size_t)N_NODES * 64 * sizeof(__half);
    float*  AGG = (float*)(wsp + o); o += (size_t)N_NODES * 64 * sizeof(float);
    int2*   csr = (int2*)(wsp + o);  o += (size_t)E_EDGES * sizeof(int2);
    int*    off = (int*)(wsp + o);   o += (size_t)(N_NODES + 1) * sizeof(int);
    int*  histM = (int*)(wsp + o);   o += (size_t)HM * sizeof(int);
    int*    hs  = (int*)(wsp + o);   o += (size_t)HM * sizeof(int);
    int*  bsums = (int*)(wsp + o);   o += (size_t)NSB * sizeof(int);
    int*   boff = (int*)(wsp + o);   o += (size_t)NSB * sizeof(int);

    dim3 blk(256);
    const int gemmGrid = (N_NODES + 63) / 64;              // 1563
    const int aggGrid  = (N_NODES * 64 + 255) / 256;       // 25000
    const int slicedGrid = 8 * ((N_NODES + 15) / 16);      // 8 * 6250 = 50000

    // ---- build CSR (once; reused by all 5 layers), zero global atomics ----
    chunk_hist<<<NCHUNK, blk, 0, stream>>>((const int4*)dst, histM);
    scan_blocks<<<NSB, blk, 0, stream>>>(histM, hs, bsums);
    scan_mid256<<<1, blk, 0, stream>>>(bsums, boff);
    scan_add<<<NSB, blk, 0, stream>>>(hs, boff);
    chunk_scatter<<<NCHUNK, blk, 0, stream>>>((const int4*)src, (const int4*)dst,
                                              (const float4*)ew, hs, tmp);
    build_csr<<<NBUCKETS, blk, 0, stream>>>(tmp, hs, off, csr);

    // ---- layer 0 (sliced H) ----
    gemm_tile<64, false, true><<<gemmGrid, blk, 0, stream>>>(x, W, H2);
    aggregate_sliced<<<slicedGrid, blk, 0, stream>>>(H2, off, csr, b, AGG);

    // ---- layers 1..3 (sliced H) ----
    for (int i = 1; i < 4; ++i) {
        gemm_tile<64, true, true><<<gemmGrid, blk, 0, stream>>>(AGG, W + (size_t)i * 64 * 64, H2);
        aggregate_sliced<<<slicedGrid, blk, 0, stream>>>(H2, off, csr, b + (size_t)i * 64, AGG);
    }

    // ---- final layer (node-major, round-5 proven path) -> d_out [N,40] ----
    gemm_tile<40, true, false><<<gemmGrid, blk, 0, stream>>>(AGG, Wout, H2);
    aggregate<40><<<aggGrid, blk, 0, stream>>>(H2, off, csr, bout, out);
}

// Round 10
// 393.305 us; speedup vs baseline: 1.9173x; 1.9173x over previous
//
#include <hip/hip_runtime.h>
#include <hip/hip_fp16.h>

#define N_NODES 100000
#define E_EDGES 1600000
#define E4 (E_EDGES / 4)                       // 400000
#define NBUCKETS ((N_NODES + 127) / 128)       // 782
#define CHUNK 8192
#define NCHUNK ((E_EDGES + CHUNK - 1) / CHUNK) // 196
#define HM (NBUCKETS * NCHUNK)                 // 153272
#define NSB ((HM + 1023) / 1024)               // 150

// ---------------------------------------------------------------------------
// GEMM: H[N,DOUT] = X[N,64] @ W[64,DOUT], fp16 output.
// FP16_IN: X is fp16 (XR from aggregate, relu already applied).
// ---------------------------------------------------------------------------
template<int DOUT, bool FP16_IN>
__global__ __launch_bounds__(256) void gemm_tile(const void* __restrict__ Xv,
                                                 const float* __restrict__ W,
                                                 __half* __restrict__ H) {
    __shared__ float Xs[64][68];
    __shared__ float Ws[64 * DOUT];
    const int tid = threadIdx.x;

    for (int i = tid; i < 64 * DOUT / 4; i += 256) {
        reinterpret_cast<float4*>(Ws)[i] = reinterpret_cast<const float4*>(W)[i];
    }

    const int row0 = blockIdx.x * 64;
#pragma unroll
    for (int p = 0; p < 4; ++p) {
        int idx = p * 256 + tid;
        int r = idx >> 4;
        int c = (idx & 15) << 2;
        float4 v = make_float4(0.f, 0.f, 0.f, 0.f);
        if (row0 + r < N_NODES) {
            if (FP16_IN) {
                const __half* Xh = (const __half*)Xv;
                uint2 raw = *reinterpret_cast<const uint2*>(Xh + (size_t)(row0 + r) * 64 + c);
                union { uint2 u; __half2 h2[2]; } pk; pk.u = raw;
                float2 a = __half22float2(pk.h2[0]);
                float2 bq = __half22float2(pk.h2[1]);
                v = make_float4(a.x, a.y, bq.x, bq.y);
            } else {
                const float* Xf = (const float*)Xv;
                v = *reinterpret_cast<const float4*>(Xf + (size_t)(row0 + r) * 64 + c);
            }
        }
        *reinterpret_cast<float4*>(&Xs[r][c]) = v;
    }
    __syncthreads();

    const int tr = (tid >> 4) << 2;
    const int tc = (tid & 15) << 2;
    if (tc < DOUT) {
        float acc[4][4];
#pragma unroll
        for (int i = 0; i < 4; ++i)
#pragma unroll
            for (int j = 0; j < 4; ++j) acc[i][j] = 0.f;

#pragma unroll 8
        for (int k = 0; k < 64; ++k) {
            float4 wv = *reinterpret_cast<const float4*>(&Ws[k * DOUT + tc]);
            float xv[4];
#pragma unroll
            for (int i = 0; i < 4; ++i) xv[i] = Xs[tr + i][k];
#pragma unroll
            for (int i = 0; i < 4; ++i) {
                acc[i][0] += xv[i] * wv.x;
                acc[i][1] += xv[i] * wv.y;
                acc[i][2] += xv[i] * wv.z;
                acc[i][3] += xv[i] * wv.w;
            }
        }
#pragma unroll
        for (int i = 0; i < 4; ++i) {
            int r = row0 + tr + i;
            if (r < N_NODES) {
                union { __half2 h2[2]; uint2 u; } pk;
                pk.h2[0] = __halves2half2(__float2half(acc[i][0]), __float2half(acc[i][1]));
                pk.h2[1] = __halves2half2(__float2half(acc[i][2]), __float2half(acc[i][3]));
                *reinterpret_cast<uint2*>(H + (size_t)r * DOUT + tc) = pk.u;
            }
        }
    }
}

// ---------------------------------------------------------------------------
// CSR build v3 (round-5 proven): chunked counting sort, NO global atomics.
// ---------------------------------------------------------------------------
__global__ __launch_bounds__(256) void chunk_hist(const int4* __restrict__ dst4,
                                                  int* __restrict__ histM) {
    __shared__ int lh[NBUCKETS];
    const int tid = threadIdx.x, c = blockIdx.x;
    for (int i = tid; i < NBUCKETS; i += 256) lh[i] = 0;
    __syncthreads();
    const int q0 = c * (CHUNK / 4);
    for (int q = tid; q < CHUNK / 4; q += 256) {
        if (q0 + q < E4) {
            int4 d = dst4[q0 + q];
            atomicAdd(&lh[d.x >> 7], 1);
            atomicAdd(&lh[d.y >> 7], 1);
            atomicAdd(&lh[d.z >> 7], 1);
            atomicAdd(&lh[d.w >> 7], 1);
        }
    }
    __syncthreads();
    for (int i = tid; i < NBUCKETS; i += 256) histM[i * NCHUNK + c] = lh[i];
}

__global__ __launch_bounds__(256) void scan_blocks(const int* __restrict__ in,
                                                   int* __restrict__ out,
                                                   int* __restrict__ bsums) {
    __shared__ int wsum[4];
    const int tid = threadIdx.x, lane = tid & 63, wv = tid >> 6;
    const int base = blockIdx.x * 1024 + tid * 4;
    int v[4];
    int s = 0;
#pragma unroll
    for (int j = 0; j < 4; ++j) {
        v[j] = (base + j < HM) ? in[base + j] : 0;
        s += v[j];
    }
    int inc = s;
#pragma unroll
    for (int o = 1; o < 64; o <<= 1) {
        int t = __shfl_up(inc, o, 64);
        if (lane >= o) inc += t;
    }
    if (lane == 63) wsum[wv] = inc;
    __syncthreads();
    int woff = 0;
    for (int w2 = 0; w2 < wv; ++w2) woff += wsum[w2];
    int run = woff + inc - s;
#pragma unroll
    for (int j = 0; j < 4; ++j) {
        if (base + j < HM) out[base + j] = run;
        run += v[j];
    }
    if (tid == 255) bsums[blockIdx.x] = woff + inc;
}

__global__ __launch_bounds__(256) void scan_mid256(const int* __restrict__ bs,
                                                   int* __restrict__ boff) {
    __shared__ int wsum[4];
    const int tid = threadIdx.x, lane = tid & 63, wv = tid >> 6;
    int v = (tid < NSB) ? bs[tid] : 0;
    int inc = v;
#pragma unroll
    for (int o = 1; o < 64; o <<= 1) {
        int t = __shfl_up(inc, o, 64);
        if (lane >= o) inc += t;
    }
    if (lane == 63) wsum[wv] = inc;
    __syncthreads();
    int woff = 0;
    for (int w2 = 0; w2 < wv; ++w2) woff += wsum[w2];
    if (tid < NSB) boff[tid] = woff + inc - v;
}

__global__ __launch_bounds__(256) void scan_add(int* __restrict__ out,
                                                const int* __restrict__ boff) {
    const int base = blockIdx.x * 1024 + threadIdx.x * 4;
    const int a = boff[blockIdx.x];
#pragma unroll
    for (int j = 0; j < 4; ++j) {
        if (base + j < HM) out[base + j] += a;
    }
}

__global__ __launch_bounds__(256) void chunk_scatter(const int4* __restrict__ src4,
                                                     const int4* __restrict__ dst4,
                                                     const float4* __restrict__ ew4,
                                                     const int* __restrict__ hs,
                                                     int2* __restrict__ tmp) {
    __shared__ int lcur[NBUCKETS];
    const int tid = threadIdx.x, c = blockIdx.x;
    for (int i = tid; i < NBUCKETS; i += 256) lcur[i] = hs[i * NCHUNK + c];
    __syncthreads();
    const int q0 = c * (CHUNK / 4);
    for (int q = tid; q < CHUNK / 4; q += 256) {
        if (q0 + q < E4) {
            int4 s = src4[q0 + q];
            int4 d = dst4[q0 + q];
            float4 w = ew4[q0 + q];
            int p0 = atomicAdd(&lcur[d.x >> 7], 1);
            tmp[p0] = make_int2(s.x | ((d.x & 127) << 17), __float_as_int(w.x));
            int p1 = atomicAdd(&lcur[d.y >> 7], 1);
            tmp[p1] = make_int2(s.y | ((d.y & 127) << 17), __float_as_int(w.y));
            int p2 = atomicAdd(&lcur[d.z >> 7], 1);
            tmp[p2] = make_int2(s.z | ((d.z & 127) << 17), __float_as_int(w.z));
            int p3 = atomicAdd(&lcur[d.w >> 7], 1);
            tmp[p3] = make_int2(s.w | ((d.w & 127) << 17), __float_as_int(w.w));
        }
    }
}

__global__ __launch_bounds__(256) void build_csr(const int2* __restrict__ tmp,
                                                 const int* __restrict__ hs,
                                                 int* __restrict__ off,
                                                 int2* __restrict__ csr) {
    __shared__ int lhist[128];
    __shared__ int lcur[128];
    __shared__ int wtot[4];
    const int b = blockIdx.x;
    const int tid = threadIdx.x, lane = tid & 63, wv = tid >> 6;
    const int base = hs[b * NCHUNK];
    const int end  = (b + 1 < NBUCKETS) ? hs[(b + 1) * NCHUNK] : E_EDGES;

    if (tid < 128) lhist[tid] = 0;
    __syncthreads();

    for (int e = base + tid; e < end; e += 256) {
        int dl = (tmp[e].x >> 17) & 127;
        atomicAdd(&lhist[dl], 1);
    }
    __syncthreads();

    int v = (tid < 128) ? lhist[tid] : 0;
    int inc = v;
#pragma unroll
    for (int o = 1; o < 64; o <<= 1) {
        int t = __shfl_up(inc, o, 64);
        if (lane >= o) inc += t;
    }
    if (lane == 63) wtot[wv] = inc;
    __syncthreads();
    if (tid < 128) {
        int excl = inc - v + ((wv == 1) ? wtot[0] : 0);
        lcur[tid] = base + excl;
        int node = b * 128 + tid;
        if (node < N_NODES) off[node] = base + excl;
    }
    if (b == NBUCKETS - 1 && tid == 0) off[N_NODES] = E_EDGES;
    __syncthreads();

    for (int e = base + tid; e < end; e += 256) {
        int2 t2 = tmp[e];
        int dl = (t2.x >> 17) & 127;
        int p = atomicAdd(&lcur[dl], 1);
        csr[p] = make_int2(t2.x & 0x1FFFF, t2.y);
    }
}

// ---------------------------------------------------------------------------
// Aggregate+bias+relu -> fp16 (interior layers). Inner loop byte-identical to
// the round-5 proven x4 named-variable pattern (no array -> no scalarization).
// ---------------------------------------------------------------------------
__global__ __launch_bounds__(256) void aggregate_relu(const __half* __restrict__ H,
                                                      const int* __restrict__ off,
                                                      const int2* __restrict__ csr,
                                                      const float* __restrict__ bvec,
                                                      __half* __restrict__ XR) {
    const int node = (int)((blockIdx.x * 256 + threadIdx.x) >> 6);
    const int lane = threadIdx.x & 63;
    if (node >= N_NODES) return;
    const int k0 = __builtin_amdgcn_readfirstlane(off[node]);
    const int k1 = __builtin_amdgcn_readfirstlane(off[node + 1]);
    float acc = bvec[lane];
    int k = k0;
    for (; k + 3 < k1; k += 4) {
        int2 e0 = csr[k], e1 = csr[k + 1], e2 = csr[k + 2], e3 = csr[k + 3];
        int s0 = __builtin_amdgcn_readfirstlane(e0.x);
        int s1 = __builtin_amdgcn_readfirstlane(e1.x);
        int s2 = __builtin_amdgcn_readfirstlane(e2.x);
        int s3 = __builtin_amdgcn_readfirstlane(e3.x);
        float h0 = __half2float(H[(size_t)s0 * 64 + lane]);
        float h1 = __half2float(H[(size_t)s1 * 64 + lane]);
        float h2 = __half2float(H[(size_t)s2 * 64 + lane]);
        float h3 = __half2float(H[(size_t)s3 * 64 + lane]);
        acc += h0 * __int_as_float(e0.y) + h1 * __int_as_float(e1.y)
             + h2 * __int_as_float(e2.y) + h3 * __int_as_float(e3.y);
    }
    for (; k < k1; ++k) {
        int2 e0 = csr[k];
        int s0 = __builtin_amdgcn_readfirstlane(e0.x);
        acc += __half2float(H[(size_t)s0 * 64 + lane]) * __int_as_float(e0.y);
    }
    XR[(size_t)node * 64 + lane] = __float2half(fmaxf(acc, 0.f));
}

// ---------------------------------------------------------------------------
// Final aggregate (DOUT=40, fp32 out, no relu) — round-5 proven.
// ---------------------------------------------------------------------------
__global__ __launch_bounds__(256) void aggregate40(const __half* __restrict__ H,
                                                   const int* __restrict__ off,
                                                   const int2* __restrict__ csr,
                                                   const float* __restrict__ bvec,
                                                   float* __restrict__ AGG) {
    const int node = (int)((blockIdx.x * 256 + threadIdx.x) >> 6);
    const int lane = threadIdx.x & 63;
    if (node >= N_NODES) return;
    const int k0 = __builtin_amdgcn_readfirstlane(off[node]);
    const int k1 = __builtin_amdgcn_readfirstlane(off[node + 1]);
    const bool active = lane < 40;
    float acc = active ? bvec[lane] : 0.f;
    int k = k0;
    for (; k + 3 < k1; k += 4) {
        int2 e0 = csr[k], e1 = csr[k + 1], e2 = csr[k + 2], e3 = csr[k + 3];
        int s0 = __builtin_amdgcn_readfirstlane(e0.x);
        int s1 = __builtin_amdgcn_readfirstlane(e1.x);
        int s2 = __builtin_amdgcn_readfirstlane(e2.x);
        int s3 = __builtin_amdgcn_readfirstlane(e3.x);
        float h0 = 0.f, h1 = 0.f, h2 = 0.f, h3 = 0.f;
        if (active) {
            h0 = __half2float(H[(size_t)s0 * 40 + lane]);
            h1 = __half2float(H[(size_t)s1 * 40 + lane]);
            h2 = __half2float(H[(size_t)s2 * 40 + lane]);
            h3 = __half2float(H[(size_t)s3 * 40 + lane]);
        }
        acc += h0 * __int_as_float(e0.y) + h1 * __int_as_float(e1.y)
             + h2 * __int_as_float(e2.y) + h3 * __int_as_float(e3.y);
    }
    for (; k < k1; ++k) {
        int2 e0 = csr[k];
        int s0 = __builtin_amdgcn_readfirstlane(e0.x);
        if (active) acc += __half2float(H[(size_t)s0 * 40 + lane]) * __int_as_float(e0.y);
    }
    if (active) AGG[(size_t)node * 40 + lane] = acc;
}

// ---------------------------------------------------------------------------
extern "C" void kernel_launch(void* const* d_in, const int* in_sizes, int n_in,
                              void* d_out, int out_size, void* d_ws, size_t ws_size,
                              hipStream_t stream) {
    const float* x    = (const float*)d_in[0];
    const float* ew   = (const float*)d_in[1];
    const float* W    = (const float*)d_in[2];   // [4,64,64]
    const float* b    = (const float*)d_in[3];   // [4,64]
    const float* Wout = (const float*)d_in[4];   // [64,40]
    const float* bout = (const float*)d_in[5];   // [40]
    const int*   src  = (const int*)d_in[6];
    const int*   dst  = (const int*)d_in[7];
    float* out = (float*)d_out;

    // workspace layout (tmp aliases H2: tmp fully consumed by build_csr
    // before the first gemm writes H2; stream order guarantees this)
    char* wsp = (char*)d_ws;
    __half* H2  = (__half*)wsp;                                   // N*64 half (12.8 MB)
    int2*   tmp = (int2*)wsp;                                     // E int2    (12.8 MB) alias
    size_t  o   = (size_t)N_NODES * 64 * sizeof(__half);
    __half* XR  = (__half*)(wsp + o); o += (size_t)N_NODES * 64 * sizeof(__half);
    int2*   csr = (int2*)(wsp + o);  o += (size_t)E_EDGES * sizeof(int2);
    int*    off = (int*)(wsp + o);   o += (size_t)(N_NODES + 1) * sizeof(int);
    int*  histM = (int*)(wsp + o);   o += (size_t)HM * sizeof(int);
    int*    hs  = (int*)(wsp + o);   o += (size_t)HM * sizeof(int);
    int*  bsums = (int*)(wsp + o);   o += (size_t)NSB * sizeof(int);
    int*   boff = (int*)(wsp + o);   o += (size_t)NSB * sizeof(int);

    dim3 blk(256);
    const int gemmGrid = (N_NODES + 63) / 64;              // 1563
    const int aggGrid  = (N_NODES * 64 + 255) / 256;       // 25000

    // ---- build CSR (once; reused by all 5 layers), zero global atomics ----
    chunk_hist<<<NCHUNK, blk, 0, stream>>>((const int4*)dst, histM);
    scan_blocks<<<NSB, blk, 0, stream>>>(histM, hs, bsums);
    scan_mid256<<<1, blk, 0, stream>>>(bsums, boff);
    scan_add<<<NSB, blk, 0, stream>>>(hs, boff);
    chunk_scatter<<<NCHUNK, blk, 0, stream>>>((const int4*)src, (const int4*)dst,
                                              (const float4*)ew, hs, tmp);
    build_csr<<<NBUCKETS, blk, 0, stream>>>(tmp, hs, off, csr);

    // ---- layer 0: H2 = x @ W0 ; XR = relu(agg(H2) + b0) ----
    gemm_tile<64, false><<<gemmGrid, blk, 0, stream>>>(x, W, H2);
    aggregate_relu<<<aggGrid, blk, 0, stream>>>(H2, off, csr, b, XR);

    // ---- layers 1..3: H2 = XR @ Wi ; XR = relu(agg(H2) + bi) ----
    for (int i = 1; i < 4; ++i) {
        gemm_tile<64, true><<<gemmGrid, blk, 0, stream>>>(XR, W + (size_t)i * 64 * 64, H2);
        aggregate_relu<<<aggGrid, blk, 0, stream>>>(H2, off, csr, b + (size_t)i * 64, XR);
    }

    // ---- final layer: H2 = XR @ Wout (N x 40) ; out = agg(H2) + bout ----
    gemm_tile<40, true><<<gemmGrid, blk, 0, stream>>>(XR, Wout, H2);
    aggregate40<<<aggGrid, blk, 0, stream>>>(H2, off, csr, bout, out);
}

// Round 11
// 390.184 us; speedup vs baseline: 1.9326x; 1.0080x over previous
//
#include <hip/hip_runtime.h>
#include <hip/hip_fp16.h>

#define N_NODES 100000
#define E_EDGES 1600000
#define E4 (E_EDGES / 4)                       // 400000
#define NBUCKETS ((N_NODES + 127) / 128)       // 782
#define CHUNK 8192
#define NCHUNK ((E_EDGES + CHUNK - 1) / CHUNK) // 196
#define HM (NBUCKETS * NCHUNK)                 // 153272
#define NSB ((HM + 1023) / 1024)               // 150

typedef _Float16 f16x8 __attribute__((ext_vector_type(8)));
typedef float    f32x4 __attribute__((ext_vector_type(4)));

// ---------------------------------------------------------------------------
// One-time weight prep: Wt[layer][c][k] = fp16(W[layer][k][c])  (4 layers)
//                       Wto[c][k]      = fp16(Wout[k][c]), c padded to 48.
// ---------------------------------------------------------------------------
__global__ __launch_bounds__(256) void conv_w(const float* __restrict__ W,
                                              const float* __restrict__ Wout,
                                              __half* __restrict__ Wt,
                                              __half* __restrict__ Wto) {
    for (int i = threadIdx.x; i < 4 * 64 * 64; i += 256) {
        int layer = i >> 12, rem = i & 4095, k = rem >> 6, c = rem & 63;
        Wt[layer * 4096 + c * 64 + k] = __float2half(W[i]);
    }
    for (int i = threadIdx.x; i < 48 * 64; i += 256) {
        int c = i >> 6, k = i & 63;
        Wto[i] = (c < 40) ? __float2half(Wout[k * 40 + c]) : __float2half(0.f);
    }
}

// ---------------------------------------------------------------------------
// MFMA GEMM: H[N,dout] = X[N,64] @ W, W given transposed fp16 [NT*16][64].
// 256 thr = 4 waves; wave computes 16 rows x NT*16 cols; K=64 = 2 MFMA steps.
// No LDS, no barriers. A-frag: lane l&15 = row, k = kb*32 + (l>>4)*8 + j
// (contiguous 16B load). B-frag: lane l&15 = col, same k-map (consistency
// between A and B makes the exact k-grouping irrelevant to the sum).
// D (m89-verified): col = lane&15, row = (lane>>4)*4 + reg.
// ---------------------------------------------------------------------------
template<int NT, bool FP32_IN>
__global__ __launch_bounds__(256) void mfma_gemm(const void* __restrict__ Xv,
                                                 const __half* __restrict__ Wt,
                                                 __half* __restrict__ H,
                                                 int dout) {
    const int tid = threadIdx.x, lane = tid & 63, wv = tid >> 6;
    const int row0 = blockIdx.x * 64 + wv * 16;
    const int rA   = row0 + (lane & 15);
    const int rr   = rA < N_NODES ? rA : N_NODES - 1;
    const int kq   = (lane >> 4) * 8;          // 0,8,16,24

    f16x8 a0, a1;
    if (FP32_IN) {
        const float* X = (const float*)Xv;
        const float4 u0 = *reinterpret_cast<const float4*>(X + (size_t)rr * 64 + kq);
        const float4 u1 = *reinterpret_cast<const float4*>(X + (size_t)rr * 64 + kq + 4);
        const float4 v0 = *reinterpret_cast<const float4*>(X + (size_t)rr * 64 + 32 + kq);
        const float4 v1 = *reinterpret_cast<const float4*>(X + (size_t)rr * 64 + 32 + kq + 4);
        a0[0] = (_Float16)u0.x; a0[1] = (_Float16)u0.y; a0[2] = (_Float16)u0.z; a0[3] = (_Float16)u0.w;
        a0[4] = (_Float16)u1.x; a0[5] = (_Float16)u1.y; a0[6] = (_Float16)u1.z; a0[7] = (_Float16)u1.w;
        a1[0] = (_Float16)v0.x; a1[1] = (_Float16)v0.y; a1[2] = (_Float16)v0.z; a1[3] = (_Float16)v0.w;
        a1[4] = (_Float16)v1.x; a1[5] = (_Float16)v1.y; a1[6] = (_Float16)v1.z; a1[7] = (_Float16)v1.w;
    } else {
        const __half* X = (const __half*)Xv;
        a0 = *reinterpret_cast<const f16x8*>(X + (size_t)rr * 64 + kq);
        a1 = *reinterpret_cast<const f16x8*>(X + (size_t)rr * 64 + 32 + kq);
    }

    f32x4 acc[NT];
#pragma unroll
    for (int t = 0; t < NT; ++t) {
        acc[t] = (f32x4){0.f, 0.f, 0.f, 0.f};
        const __half* wb = Wt + (size_t)(t * 16 + (lane & 15)) * 64;
        f16x8 b0 = *reinterpret_cast<const f16x8*>(wb + kq);
        f16x8 b1 = *reinterpret_cast<const f16x8*>(wb + 32 + kq);
        acc[t] = __builtin_amdgcn_mfma_f32_16x16x32_f16(a0, b0, acc[t], 0, 0, 0);
        acc[t] = __builtin_amdgcn_mfma_f32_16x16x32_f16(a1, b1, acc[t], 0, 0, 0);
    }

    const int colb = lane & 15;
    const int rowq = row0 + (lane >> 4) * 4;
#pragma unroll
    for (int t = 0; t < NT; ++t) {
        const int col = t * 16 + colb;
        if (col < dout) {
#pragma unroll
            for (int r = 0; r < 4; ++r) {
                const int row = rowq + r;
                if (row < N_NODES)
                    H[(size_t)row * dout + col] = __float2half(acc[t][r]);
            }
        }
    }
}

// ---------------------------------------------------------------------------
// CSR build v3 (round-5 proven): chunked counting sort, NO global atomics.
// ---------------------------------------------------------------------------
__global__ __launch_bounds__(256) void chunk_hist(const int4* __restrict__ dst4,
                                                  int* __restrict__ histM) {
    __shared__ int lh[NBUCKETS];
    const int tid = threadIdx.x, c = blockIdx.x;
    for (int i = tid; i < NBUCKETS; i += 256) lh[i] = 0;
    __syncthreads();
    const int q0 = c * (CHUNK / 4);
    for (int q = tid; q < CHUNK / 4; q += 256) {
        if (q0 + q < E4) {
            int4 d = dst4[q0 + q];
            atomicAdd(&lh[d.x >> 7], 1);
            atomicAdd(&lh[d.y >> 7], 1);
            atomicAdd(&lh[d.z >> 7], 1);
            atomicAdd(&lh[d.w >> 7], 1);
        }
    }
    __syncthreads();
    for (int i = tid; i < NBUCKETS; i += 256) histM[i * NCHUNK + c] = lh[i];
}

__global__ __launch_bounds__(256) void scan_blocks(const int* __restrict__ in,
                                                   int* __restrict__ out,
                                                   int* __restrict__ bsums) {
    __shared__ int wsum[4];
    const int tid = threadIdx.x, lane = tid & 63, wv = tid >> 6;
    const int base = blockIdx.x * 1024 + tid * 4;
    int v[4];
    int s = 0;
#pragma unroll
    for (int j = 0; j < 4; ++j) {
        v[j] = (base + j < HM) ? in[base + j] : 0;
        s += v[j];
    }
    int inc = s;
#pragma unroll
    for (int o = 1; o < 64; o <<= 1) {
        int t = __shfl_up(inc, o, 64);
        if (lane >= o) inc += t;
    }
    if (lane == 63) wsum[wv] = inc;
    __syncthreads();
    int woff = 0;
    for (int w2 = 0; w2 < wv; ++w2) woff += wsum[w2];
    int run = woff + inc - s;
#pragma unroll
    for (int j = 0; j < 4; ++j) {
        if (base + j < HM) out[base + j] = run;
        run += v[j];
    }
    if (tid == 255) bsums[blockIdx.x] = woff + inc;
}

__global__ __launch_bounds__(256) void scan_mid256(const int* __restrict__ bs,
                                                   int* __restrict__ boff) {
    __shared__ int wsum[4];
    const int tid = threadIdx.x, lane = tid & 63, wv = tid >> 6;
    int v = (tid < NSB) ? bs[tid] : 0;
    int inc = v;
#pragma unroll
    for (int o = 1; o < 64; o <<= 1) {
        int t = __shfl_up(inc, o, 64);
        if (lane >= o) inc += t;
    }
    if (lane == 63) wsum[wv] = inc;
    __syncthreads();
    int woff = 0;
    for (int w2 = 0; w2 < wv; ++w2) woff += wsum[w2];
    if (tid < NSB) boff[tid] = woff + inc - v;
}

__global__ __launch_bounds__(256) void scan_add(int* __restrict__ out,
                                                const int* __restrict__ boff) {
    const int base = blockIdx.x * 1024 + threadIdx.x * 4;
    const int a = boff[blockIdx.x];
#pragma unroll
    for (int j = 0; j < 4; ++j) {
        if (base + j < HM) out[base + j] += a;
    }
}

__global__ __launch_bounds__(256) void chunk_scatter(const int4* __restrict__ src4,
                                                     const int4* __restrict__ dst4,
                                                     const float4* __restrict__ ew4,
                                                     const int* __restrict__ hs,
                                                     int2* __restrict__ tmp) {
    __shared__ int lcur[NBUCKETS];
    const int tid = threadIdx.x, c = blockIdx.x;
    for (int i = tid; i < NBUCKETS; i += 256) lcur[i] = hs[i * NCHUNK + c];
    __syncthreads();
    const int q0 = c * (CHUNK / 4);
    for (int q = tid; q < CHUNK / 4; q += 256) {
        if (q0 + q < E4) {
            int4 s = src4[q0 + q];
            int4 d = dst4[q0 + q];
            float4 w = ew4[q0 + q];
            int p0 = atomicAdd(&lcur[d.x >> 7], 1);
            tmp[p0] = make_int2(s.x | ((d.x & 127) << 17), __float_as_int(w.x));
            int p1 = atomicAdd(&lcur[d.y >> 7], 1);
            tmp[p1] = make_int2(s.y | ((d.y & 127) << 17), __float_as_int(w.y));
            int p2 = atomicAdd(&lcur[d.z >> 7], 1);
            tmp[p2] = make_int2(s.z | ((d.z & 127) << 17), __float_as_int(w.z));
            int p3 = atomicAdd(&lcur[d.w >> 7], 1);
            tmp[p3] = make_int2(s.w | ((d.w & 127) << 17), __float_as_int(w.w));
        }
    }
}

__global__ __launch_bounds__(256) void build_csr(const int2* __restrict__ tmp,
                                                 const int* __restrict__ hs,
                                                 int* __restrict__ off,
                                                 int2* __restrict__ csr) {
    __shared__ int lhist[128];
    __shared__ int lcur[128];
    __shared__ int wtot[4];
    const int b = blockIdx.x;
    const int tid = threadIdx.x, lane = tid & 63, wv = tid >> 6;
    const int base = hs[b * NCHUNK];
    const int end  = (b + 1 < NBUCKETS) ? hs[(b + 1) * NCHUNK] : E_EDGES;

    if (tid < 128) lhist[tid] = 0;
    __syncthreads();

    for (int e = base + tid; e < end; e += 256) {
        int dl = (tmp[e].x >> 17) & 127;
        atomicAdd(&lhist[dl], 1);
    }
    __syncthreads();

    int v = (tid < 128) ? lhist[tid] : 0;
    int inc = v;
#pragma unroll
    for (int o = 1; o < 64; o <<= 1) {
        int t = __shfl_up(inc, o, 64);
        if (lane >= o) inc += t;
    }
    if (lane == 63) wtot[wv] = inc;
    __syncthreads();
    if (tid < 128) {
        int excl = inc - v + ((wv == 1) ? wtot[0] : 0);
        lcur[tid] = base + excl;
        int node = b * 128 + tid;
        if (node < N_NODES) off[node] = base + excl;
    }
    if (b == NBUCKETS - 1 && tid == 0) off[N_NODES] = E_EDGES;
    __syncthreads();

    for (int e = base + tid; e < end; e += 256) {
        int2 t2 = tmp[e];
        int dl = (t2.x >> 17) & 127;
        int p = atomicAdd(&lcur[dl], 1);
        csr[p] = make_int2(t2.x & 0x1FFFF, t2.y);
    }
}

// ---------------------------------------------------------------------------
// Aggregate+bias+relu -> fp16 (interior layers). Round-5 proven x4 pattern.
// ---------------------------------------------------------------------------
__global__ __launch_bounds__(256) void aggregate_relu(const __half* __restrict__ H,
                                                      const int* __restrict__ off,
                                                      const int2* __restrict__ csr,
                                                      const float* __restrict__ bvec,
                                                      __half* __restrict__ XR) {
    const int node = (int)((blockIdx.x * 256 + threadIdx.x) >> 6);
    const int lane = threadIdx.x & 63;
    if (node >= N_NODES) return;
    const int k0 = __builtin_amdgcn_readfirstlane(off[node]);
    const int k1 = __builtin_amdgcn_readfirstlane(off[node + 1]);
    float acc = bvec[lane];
    int k = k0;
    for (; k + 3 < k1; k += 4) {
        int2 e0 = csr[k], e1 = csr[k + 1], e2 = csr[k + 2], e3 = csr[k + 3];
        int s0 = __builtin_amdgcn_readfirstlane(e0.x);
        int s1 = __builtin_amdgcn_readfirstlane(e1.x);
        int s2 = __builtin_amdgcn_readfirstlane(e2.x);
        int s3 = __builtin_amdgcn_readfirstlane(e3.x);
        float h0 = __half2float(H[(size_t)s0 * 64 + lane]);
        float h1 = __half2float(H[(size_t)s1 * 64 + lane]);
        float h2 = __half2float(H[(size_t)s2 * 64 + lane]);
        float h3 = __half2float(H[(size_t)s3 * 64 + lane]);
        acc += h0 * __int_as_float(e0.y) + h1 * __int_as_float(e1.y)
             + h2 * __int_as_float(e2.y) + h3 * __int_as_float(e3.y);
    }
    for (; k < k1; ++k) {
        int2 e0 = csr[k];
        int s0 = __builtin_amdgcn_readfirstlane(e0.x);
        acc += __half2float(H[(size_t)s0 * 64 + lane]) * __int_as_float(e0.y);
    }
    XR[(size_t)node * 64 + lane] = __float2half(fmaxf(acc, 0.f));
}

// ---------------------------------------------------------------------------
// Final aggregate (DOUT=40, fp32 out, no relu) — round-5 proven.
// ---------------------------------------------------------------------------
__global__ __launch_bounds__(256) void aggregate40(const __half* __restrict__ H,
                                                   const int* __restrict__ off,
                                                   const int2* __restrict__ csr,
                                                   const float* __restrict__ bvec,
                                                   float* __restrict__ AGG) {
    const int node = (int)((blockIdx.x * 256 + threadIdx.x) >> 6);
    const int lane = threadIdx.x & 63;
    if (node >= N_NODES) return;
    const int k0 = __builtin_amdgcn_readfirstlane(off[node]);
    const int k1 = __builtin_amdgcn_readfirstlane(off[node + 1]);
    const bool active = lane < 40;
    float acc = active ? bvec[lane] : 0.f;
    int k = k0;
    for (; k + 3 < k1; k += 4) {
        int2 e0 = csr[k], e1 = csr[k + 1], e2 = csr[k + 2], e3 = csr[k + 3];
        int s0 = __builtin_amdgcn_readfirstlane(e0.x);
        int s1 = __builtin_amdgcn_readfirstlane(e1.x);
        int s2 = __builtin_amdgcn_readfirstlane(e2.x);
        int s3 = __builtin_amdgcn_readfirstlane(e3.x);
        float h0 = 0.f, h1 = 0.f, h2 = 0.f, h3 = 0.f;
        if (active) {
            h0 = __half2float(H[(size_t)s0 * 40 + lane]);
            h1 = __half2float(H[(size_t)s1 * 40 + lane]);
            h2 = __half2float(H[(size_t)s2 * 40 + lane]);
            h3 = __half2float(H[(size_t)s3 * 40 + lane]);
        }
        acc += h0 * __int_as_float(e0.y) + h1 * __int_as_float(e1.y)
             + h2 * __int_as_float(e2.y) + h3 * __int_as_float(e3.y);
    }
    for (; k < k1; ++k) {
        int2 e0 = csr[k];
        int s0 = __builtin_amdgcn_readfirstlane(e0.x);
        if (active) acc += __half2float(H[(size_t)s0 * 40 + lane]) * __int_as_float(e0.y);
    }
    if (active) AGG[(size_t)node * 40 + lane] = acc;
}

// ---------------------------------------------------------------------------
extern "C" void kernel_launch(void* const* d_in, const int* in_sizes, int n_in,
                              void* d_out, int out_size, void* d_ws, size_t ws_size,
                              hipStream_t stream) {
    const float* x    = (const float*)d_in[0];
    const float* ew   = (const float*)d_in[1];
    const float* W    = (const float*)d_in[2];   // [4,64,64]
    const float* b    = (const float*)d_in[3];   // [4,64]
    const float* Wout = (const float*)d_in[4];   // [64,40]
    const float* bout = (const float*)d_in[5];   // [40]
    const int*   src  = (const int*)d_in[6];
    const int*   dst  = (const int*)d_in[7];
    float* out = (float*)d_out;

    // workspace layout (tmp aliases H2: tmp fully consumed by build_csr
    // before the first gemm writes H2; stream order guarantees this)
    char* wsp = (char*)d_ws;
    __half* H2  = (__half*)wsp;                                   // N*64 half (12.8 MB)
    int2*   tmp = (int2*)wsp;                                     // E int2    (12.8 MB) alias
    size_t  o   = (size_t)N_NODES * 64 * sizeof(__half);
    __half* XR  = (__half*)(wsp + o); o += (size_t)N_NODES * 64 * sizeof(__half);
    int2*   csr = (int2*)(wsp + o);  o += (size_t)E_EDGES * sizeof(int2);
    int*    off = (int*)(wsp + o);   o += (size_t)(N_NODES + 1) * sizeof(int);
    int*  histM = (int*)(wsp + o);   o += (size_t)HM * sizeof(int);
    int*    hs  = (int*)(wsp + o);   o += (size_t)HM * sizeof(int);
    int*  bsums = (int*)(wsp + o);   o += (size_t)NSB * sizeof(int);
    int*   boff = (int*)(wsp + o);   o += (size_t)NSB * sizeof(int);
    __half* Wt  = (__half*)(wsp + o); o += (size_t)4 * 4096 * sizeof(__half);
    __half* Wto = (__half*)(wsp + o); o += (size_t)48 * 64 * sizeof(__half);

    dim3 blk(256);
    const int gemmGrid = (N_NODES + 63) / 64;              // 1563
    const int aggGrid  = (N_NODES * 64 + 255) / 256;       // 25000

    // ---- one-time prep: fp16 transposed weights ----
    conv_w<<<1, blk, 0, stream>>>(W, Wout, Wt, Wto);

    // ---- build CSR (once; reused by all 5 layers), zero global atomics ----
    chunk_hist<<<NCHUNK, blk, 0, stream>>>((const int4*)dst, histM);
    scan_blocks<<<NSB, blk, 0, stream>>>(histM, hs, bsums);
    scan_mid256<<<1, blk, 0, stream>>>(bsums, boff);
    scan_add<<<NSB, blk, 0, stream>>>(hs, boff);
    chunk_scatter<<<NCHUNK, blk, 0, stream>>>((const int4*)src, (const int4*)dst,
                                              (const float4*)ew, hs, tmp);
    build_csr<<<NBUCKETS, blk, 0, stream>>>(tmp, hs, off, csr);

    // ---- layer 0: H2 = fp16(x) @ W0 ; XR = relu(agg(H2) + b0) ----
    mfma_gemm<4, true><<<gemmGrid, blk, 0, stream>>>(x, Wt, H2, 64);
    aggregate_relu<<<aggGrid, blk, 0, stream>>>(H2, off, csr, b, XR);

    // ---- layers 1..3: H2 = XR @ Wi ; XR = relu(agg(H2) + bi) ----
    for (int i = 1; i < 4; ++i) {
        mfma_gemm<4, false><<<gemmGrid, blk, 0, stream>>>(XR, Wt + (size_t)i * 4096, H2, 64);
        aggregate_relu<<<aggGrid, blk, 0, stream>>>(H2, off, csr, b + (size_t)i * 64, XR);
    }

    // ---- final layer: H2 = XR @ Wout (N x 40) ; out = agg(H2) + bout ----
    mfma_gemm<3, false><<<gemmGrid, blk, 0, stream>>>(XR, Wto, H2, 40);
    aggregate40<<<aggGrid, blk, 0, stream>>>(H2, off, csr, bout, out);
}